// Round 9
// baseline (60.329 us; speedup 1.0000x reference)
//
#include <hip/hip_runtime.h>
#include <stdint.h>
#include <math.h>

#define NN 4096
#define DIN 1024
#define DOUT 512
#define ALPHA 0.2f

typedef __attribute__((ext_vector_type(8))) short short8;
typedef __attribute__((ext_vector_type(4))) float f32x4;

__device__ __forceinline__ unsigned short f2bf(float f) {
    uint32_t u = __float_as_uint(f);
    u += 0x7fffu + ((u >> 16) & 1u);
    return (unsigned short)(u >> 16);
}

__device__ __forceinline__ void async16(const void* g, void* l) {
    __builtin_amdgcn_global_load_lds(
        (const __attribute__((address_space(1))) uint32_t*)g,
        (__attribute__((address_space(3))) uint32_t*)l, 16, 0, 0);
}

// ---------------- K1: fused prep.
// blocks 0..255:   wt = bf16(W^T) pre-swizzled (block 0 also zeroes colacc)
// blocks 256..511: wa1 = Wf@a1, wa2 = Wf@a2 (wave per row)
__global__ __launch_bounds__(256) void k_prep(const float* __restrict__ W,
                                              const float* __restrict__ Wf,
                                              const float* __restrict__ a1,
                                              const float* __restrict__ a2,
                                              unsigned short* __restrict__ wt,
                                              float* __restrict__ wa1,
                                              float* __restrict__ wa2,
                                              float* __restrict__ colacc) {
    int tid = threadIdx.x;
    if (blockIdx.x == 0) {
#pragma unroll
        for (int i = 0; i < 16; ++i) colacc[tid + 256 * i] = 0.f;
    }
    if (blockIdx.x < 256) {
        int bx = blockIdx.x & 7, gy = blockIdx.x >> 3;
        int n = bx * 64 + (tid & 63);
        int g = gy * 4 + (tid >> 6);          // k-granule 0..127
        float v[8];
#pragma unroll
        for (int j = 0; j < 8; ++j) v[j] = W[(size_t)(g * 8 + j) * DOUT + n];
        union { unsigned short u[8]; uint4 q; } pk;
#pragma unroll
        for (int j = 0; j < 8; ++j) pk.u[j] = f2bf(v[j]);
        int sw = (n >> 1) & 3;
        int p  = (g & ~3) | ((g & 3) ^ sw);
        *(uint4*)(wt + (size_t)n * DIN + p * 8) = pk.q;
    } else {
        int row  = (blockIdx.x - 256) * 4 + (tid >> 6);
        int lane = tid & 63;
        const float* wr = Wf + (size_t)row * DOUT;
        float s1 = 0.f, s2 = 0.f;
        for (int k = lane; k < DOUT; k += 64) {
            float w = wr[k];
            s1 += w * a1[k];
            s2 += w * a2[k];
        }
        for (int off = 32; off; off >>= 1) {
            s1 += __shfl_down(s1, off);
            s2 += __shfl_down(s2, off);
        }
        if (lane == 0) { wa1[row] = s1; wa2[row] = s2; }
    }
}

// ---------------- K2: f1,f2 GEMV + x -> bf16 (pre-swizzled), wave per row
__global__ __launch_bounds__(256) void k_fx(const float* __restrict__ x,
    const float* __restrict__ wa1, const float* __restrict__ wa2,
    const float* __restrict__ b1, const float* __restrict__ b2,
    float* __restrict__ f1, float* __restrict__ f2,
    unsigned short* __restrict__ xb) {
    int row  = blockIdx.x * 4 + (threadIdx.x >> 6);
    int lane = threadIdx.x & 63;
    const float* xr = x + (size_t)row * DIN + lane * 16;
    float xv[16];
    *(float4*)&xv[0]  = *(const float4*)(xr);
    *(float4*)&xv[4]  = *(const float4*)(xr + 4);
    *(float4*)&xv[8]  = *(const float4*)(xr + 8);
    *(float4*)&xv[12] = *(const float4*)(xr + 12);
    asm volatile("" ::: "memory");   // keep all 4 loads in flight
    const float* w1 = wa1 + lane * 16;
    const float* w2 = wa2 + lane * 16;
    float s1 = 0.f, s2 = 0.f;
#pragma unroll
    for (int j = 0; j < 16; ++j) {
        s1 += xv[j] * w1[j];
        s2 += xv[j] * w2[j];
    }
    union { unsigned short u[8]; uint4 q; } pk0, pk1;
#pragma unroll
    for (int j = 0; j < 8; ++j) { pk0.u[j] = f2bf(xv[j]); pk1.u[j] = f2bf(xv[8 + j]); }
    int sw = (row >> 1) & 3;
    int g0 = lane * 2, g1 = lane * 2 + 1;
    int p0 = (g0 & ~3) | ((g0 & 3) ^ sw);
    int p1 = (g1 & ~3) | ((g1 & 3) ^ sw);
    unsigned short* xrow = xb + (size_t)row * DIN;
    *(uint4*)(xrow + p0 * 8) = pk0.q;
    *(uint4*)(xrow + p1 * 8) = pk1.q;
    for (int off = 32; off; off >>= 1) {
        s1 += __shfl_down(s1, off);
        s2 += __shfl_down(s2, off);
    }
    if (lane == 0) { f1[row] = s1 + b1[0]; f2[row] = s2 + b2[0]; }
}

// ---------------- K3: streaming softmax Z + fused colsum atomics.
// 2 rows/block (2048 blocks). 8 independent float4 loads forced in-flight;
// branchless mask; first walk -> Z; after reduce, second walk scatters
// exp*rZ into colacc via atomicAdd (~21 atomics/row).
__global__ __launch_bounds__(256) void k_stats(const float* __restrict__ adj,
                                               const float* __restrict__ f1,
                                               const float* __restrict__ f2,
                                               float* __restrict__ rZ_out,
                                               float* __restrict__ colacc) {
    int tid = threadIdx.x;
    int row0 = blockIdx.x * 2;
    const float4* a0 = (const float4*)(adj + (size_t)row0 * NN);
    const float4* a1 = (const float4*)(adj + (size_t)(row0 + 1) * NN);
    float4 v0 = a0[tid];       float4 v1 = a0[tid + 256];
    float4 v2 = a0[tid + 512]; float4 v3 = a0[tid + 768];
    float4 v4 = a1[tid];       float4 v5 = a1[tid + 256];
    float4 v6 = a1[tid + 512]; float4 v7 = a1[tid + 768];
    asm volatile("" ::: "memory");   // all 8 loads issued before any use
    unsigned int m0 = 0, m1 = 0;
#define MB(M, V, J)                                            \
    M |= (((V).x != 0.f) ? 1u : 0u) << (4 * (J));              \
    M |= (((V).y != 0.f) ? 1u : 0u) << (4 * (J) + 1);          \
    M |= (((V).z != 0.f) ? 1u : 0u) << (4 * (J) + 2);          \
    M |= (((V).w != 0.f) ? 1u : 0u) << (4 * (J) + 3);
    MB(m0, v0, 0) MB(m0, v1, 1) MB(m0, v2, 2) MB(m0, v3, 3)
    MB(m1, v4, 0) MB(m1, v5, 1) MB(m1, v6, 2) MB(m1, v7, 3)
#undef MB
    float f10 = f1[row0], f11 = f1[row0 + 1];
    float z0 = 0.f, z1 = 0.f;
    unsigned int w = m0;
    while (w) {
        int b = __builtin_ctz(w); w &= w - 1;
        float l = f10 + f2[4 * tid + 1024 * (b >> 2) + (b & 3)];
        z0 += __expf((l >= 0.f) ? l : ALPHA * l);
    }
    w = m1;
    while (w) {
        int b = __builtin_ctz(w); w &= w - 1;
        float l = f11 + f2[4 * tid + 1024 * (b >> 2) + (b & 3)];
        z1 += __expf((l >= 0.f) ? l : ALPHA * l);
    }
    int lane = tid & 63, wid = tid >> 6;
    for (int off = 32; off; off >>= 1) {
        z0 += __shfl_down(z0, off);
        z1 += __shfl_down(z1, off);
    }
    __shared__ float red[8];
    if (lane == 0) { red[wid] = z0; red[4 + wid] = z1; }
    __syncthreads();
    float rZ0 = 1.0f / (red[0] + red[1] + red[2] + red[3]);
    float rZ1 = 1.0f / (red[4] + red[5] + red[6] + red[7]);
    if (tid == 0) rZ_out[row0]     = rZ0;
    if (tid == 1) rZ_out[row0 + 1] = rZ1;
    // second walk: scatter coefs into colacc
    w = m0;
    while (w) {
        int b = __builtin_ctz(w); w &= w - 1;
        int j = 4 * tid + 1024 * (b >> 2) + (b & 3);
        float l = f10 + f2[j];
        atomicAdd(&colacc[j], __expf((l >= 0.f) ? l : ALPHA * l) * rZ0);
    }
    w = m1;
    while (w) {
        int b = __builtin_ctz(w); w &= w - 1;
        int j = 4 * tid + 1024 * (b >> 2) + (b & 3);
        float l = f11 + f2[j];
        atomicAdd(&colacc[j], __expf((l >= 0.f) ? l : ALPHA * l) * rZ1);
    }
}

// ---------------- K4: out = relu(diag(s) @ (xb @ Wt^T)), bf16 MFMA.
// 128x64 tile, BK=32, EIGHT waves (512 thr) -> 2 waves/SIMD for latency
// hiding. s computed in prologue from colacc/rZ (parallel 4-load per thread).
__global__ __launch_bounds__(512) void k_gemm(const unsigned short* __restrict__ xb,
                                              const unsigned short* __restrict__ wt,
                                              const float* __restrict__ f1,
                                              const float* __restrict__ f2,
                                              const float* __restrict__ rZ,
                                              const float* __restrict__ colacc,
                                              float* __restrict__ out) {
    __shared__ __align__(16) unsigned short As[2][128][32];
    __shared__ __align__(16) unsigned short Bs[2][64][32];
    __shared__ float s_lds[128];
    // XCD-chunked block remap
    int lid = blockIdx.y * gridDim.x + blockIdx.x;   // 0..255
    int xcd = lid & 7, idx = lid >> 3;
    int by = xcd * 4 + (idx & 3);                    // 0..31
    int bx = idx >> 2;                               // 0..7
    int bm = by * 128, bn = bx * 64;

    int tid = threadIdx.x, wid = tid >> 6, lane = tid & 63;
    int wr = wid >> 1, wc = wid & 1;                 // 4x2 wave grid of 32x32

    int srow = lane >> 2, sg = lane & 3;
    const unsigned short* ga0 = xb + (size_t)(bm + wid * 16 + srow) * DIN + sg * 8;
    const unsigned short* gb0 = wt + (size_t)(bn + wid * 16 + srow) * DIN + sg * 8;

    int r15 = lane & 15, gl = lane >> 4;
    int gofs = (gl ^ ((r15 >> 1) & 3)) * 8;          // XOR-swizzled read offset

    f32x4 acc[2][2] = {};

#define STAGE(BUF, K0) do {                                              \
        async16(ga0 + (K0), &As[BUF][wid * 16][0]);                      \
        if (tid < 256) async16(gb0 + (K0), &Bs[BUF][wid * 16][0]);       \
    } while (0)

#define COMPUTE(BUF) do {                                                \
        const unsigned short* pa = &As[BUF][wr * 32 + r15][gofs];        \
        const unsigned short* pb = &Bs[BUF][wc * 32 + r15][gofs];        \
        short8 af0 = *(const short8*)(pa);                               \
        short8 af1 = *(const short8*)(pa + 16 * 32);                     \
        short8 bf0 = *(const short8*)(pb);                               \
        short8 bf1 = *(const short8*)(pb + 16 * 32);                     \
        acc[0][0] = __builtin_amdgcn_mfma_f32_16x16x32_bf16(af0, bf0, acc[0][0], 0, 0, 0); \
        acc[0][1] = __builtin_amdgcn_mfma_f32_16x16x32_bf16(af0, bf1, acc[0][1], 0, 0, 0); \
        acc[1][0] = __builtin_amdgcn_mfma_f32_16x16x32_bf16(af1, bf0, acc[1][0], 0, 0, 0); \
        acc[1][1] = __builtin_amdgcn_mfma_f32_16x16x32_bf16(af1, bf1, acc[1][1], 0, 0, 0); \
    } while (0)

    STAGE(0, 0);
    // s for this tile's 128 rows: 4 parallel loads/thread, hides under vmcnt
    if (tid < 128) {
        int r = bm + tid;
        float l   = f1[r] + f2[r];
        float cjj = __expf((l >= 0.f) ? l : ALPHA * l) * rZ[r];
        s_lds[tid] = (cjj + 1.0f) / (1.5f + 0.5f * colacc[r]);
    }
    asm volatile("s_waitcnt vmcnt(0)" ::: "memory");
    __syncthreads();
    int cur = 0;
    for (int t = 0; t < (DIN / 32) - 1; ++t) {
        STAGE(cur ^ 1, (t + 1) * 32);
        COMPUTE(cur);
        asm volatile("s_waitcnt vmcnt(0)" ::: "memory");
        __syncthreads();
        cur ^= 1;
    }
    COMPUTE(cur);

#pragma unroll
    for (int mi = 0; mi < 2; ++mi) {
        int lrow0 = wr * 32 + mi * 16 + gl * 4;
#pragma unroll
        for (int ni = 0; ni < 2; ++ni) {
            int ccol = bn + wc * 32 + ni * 16 + r15;
#pragma unroll
            for (int r = 0; r < 4; ++r) {
                int lrow = lrow0 + r;
                float v = acc[mi][ni][r] * s_lds[lrow];
                out[(size_t)(bm + lrow) * DOUT + ccol] = fmaxf(v, 0.f);
            }
        }
    }
#undef STAGE
#undef COMPUTE
}

extern "C" void kernel_launch(void* const* d_in, const int* in_sizes, int n_in,
                              void* d_out, int out_size, void* d_ws, size_t ws_size,
                              hipStream_t stream) {
    const float* x   = (const float*)d_in[0];
    const float* adj = (const float*)d_in[1];
    const float* Wf  = (const float*)d_in[2];
    const float* a1  = (const float*)d_in[3];
    const float* b1  = (const float*)d_in[4];
    const float* a2  = (const float*)d_in[5];
    const float* b2  = (const float*)d_in[6];
    const float* W   = (const float*)d_in[7];
    float* out = (float*)d_out;

    char* w = (char*)d_ws;
    float* wa1 = (float*)(w + 0);
    float* wa2 = (float*)(w + 4096);
    float* f1  = (float*)(w + 16384);
    float* f2  = (float*)(w + 32768);
    float* rZ  = (float*)(w + 49152);
    float* colacc = (float*)(w + 65536);
    unsigned short* xb = (unsigned short*)(w + 2195456);             // 8 MB
    unsigned short* wt = (unsigned short*)(w + 10584064);            // 1 MB

    k_prep<<<512, 256, 0, stream>>>(W, Wf, a1, a2, wt, wa1, wa2, colacc);
    k_fx<<<1024, 256, 0, stream>>>(x, wa1, wa2, b1, b2, f1, f2, xb);
    k_stats<<<2048, 256, 0, stream>>>(adj, f1, f2, rZ, colacc);
    dim3 gg(8, 32);
    k_gemm<<<gg, 512, 0, stream>>>(xb, wt, f1, f2, rZ, colacc, out);
}

// Round 10
// 51.060 us; speedup vs baseline: 1.1815x; 1.1815x over previous
//
#include <hip/hip_runtime.h>
#include <stdint.h>
#include <math.h>

#define NN 4096
#define DIN 1024
#define DOUT 512
#define ALPHA 0.2f

typedef __attribute__((ext_vector_type(8))) short short8;
typedef __attribute__((ext_vector_type(4))) float f32x4;

__device__ __forceinline__ unsigned short f2bf(float f) {
    uint32_t u = __float_as_uint(f);
    u += 0x7fffu + ((u >> 16) & 1u);
    return (unsigned short)(u >> 16);
}

__device__ __forceinline__ void async16(const void* g, void* l) {
    __builtin_amdgcn_global_load_lds(
        (const __attribute__((address_space(1))) uint32_t*)g,
        (__attribute__((address_space(3))) uint32_t*)l, 16, 0, 0);
}

// ---------------- K1: fused prep.
// blocks 0..255:   wt = bf16(W^T) with pre-swizzled granules
// blocks 256..511: wa1 = Wf@a1, wa2 = Wf@a2 (wave per row)
__global__ __launch_bounds__(256) void k_prep(const float* __restrict__ W,
                                              const float* __restrict__ Wf,
                                              const float* __restrict__ a1,
                                              const float* __restrict__ a2,
                                              unsigned short* __restrict__ wt,
                                              float* __restrict__ wa1,
                                              float* __restrict__ wa2) {
    int tid = threadIdx.x;
    if (blockIdx.x < 256) {
        int bx = blockIdx.x & 7, gy = blockIdx.x >> 3;
        int n = bx * 64 + (tid & 63);
        int g = gy * 4 + (tid >> 6);          // k-granule 0..127
        float v[8];
#pragma unroll
        for (int j = 0; j < 8; ++j) v[j] = W[(size_t)(g * 8 + j) * DOUT + n];
        union { unsigned short u[8]; uint4 q; } pk;
#pragma unroll
        for (int j = 0; j < 8; ++j) pk.u[j] = f2bf(v[j]);
        int sw = (n >> 1) & 3;
        int p  = (g & ~3) | ((g & 3) ^ sw);
        *(uint4*)(wt + (size_t)n * DIN + p * 8) = pk.q;
    } else {
        int row  = (blockIdx.x - 256) * 4 + (tid >> 6);
        int lane = tid & 63;
        const float* wr = Wf + (size_t)row * DOUT;
        float s1 = 0.f, s2 = 0.f;
        for (int k = lane; k < DOUT; k += 64) {
            float w = wr[k];
            s1 += w * a1[k];
            s2 += w * a2[k];
        }
        for (int off = 32; off; off >>= 1) {
            s1 += __shfl_down(s1, off);
            s2 += __shfl_down(s2, off);
        }
        if (lane == 0) { wa1[row] = s1; wa2[row] = s2; }
    }
}

// ---------------- K2: fused mask-builder + fx.
// blocks 0..2047: PURE adj stream -> u16 masks (2 rows/block, 8 forced loads)
// blocks 2048..3071: f1,f2 GEMV + x -> bf16 (wave per row)
__global__ __launch_bounds__(256) void k_maskfx(const float* __restrict__ adj,
    const float* __restrict__ x,
    const float* __restrict__ wa1, const float* __restrict__ wa2,
    const float* __restrict__ b1, const float* __restrict__ b2,
    float* __restrict__ f1, float* __restrict__ f2,
    unsigned short* __restrict__ xb,
    unsigned short* __restrict__ bits16) {
    int tid = threadIdx.x;
    if (blockIdx.x < 2048) {
        int row0 = blockIdx.x * 2;
        const float4* a0 = (const float4*)(adj + (size_t)row0 * NN);
        const float4* a1v = (const float4*)(adj + (size_t)(row0 + 1) * NN);
        float4 v0 = a0[tid];        float4 v1 = a0[tid + 256];
        float4 v2 = a0[tid + 512];  float4 v3 = a0[tid + 768];
        float4 v4 = a1v[tid];       float4 v5 = a1v[tid + 256];
        float4 v6 = a1v[tid + 512]; float4 v7 = a1v[tid + 768];
        asm volatile("" ::: "memory");   // all 8 loads issued before any use
        unsigned int m0 = 0, m1 = 0;
#define MB(M, V, J)                                            \
        M |= (((V).x != 0.f) ? 1u : 0u) << (4 * (J));          \
        M |= (((V).y != 0.f) ? 1u : 0u) << (4 * (J) + 1);      \
        M |= (((V).z != 0.f) ? 1u : 0u) << (4 * (J) + 2);      \
        M |= (((V).w != 0.f) ? 1u : 0u) << (4 * (J) + 3);
        MB(m0, v0, 0) MB(m0, v1, 1) MB(m0, v2, 2) MB(m0, v3, 3)
        MB(m1, v4, 0) MB(m1, v5, 1) MB(m1, v6, 2) MB(m1, v7, 3)
#undef MB
        bits16[(size_t)row0 * 256 + tid]       = (unsigned short)m0;
        bits16[(size_t)row0 * 256 + 256 + tid] = (unsigned short)m1;
    } else {
        int row  = (blockIdx.x - 2048) * 4 + (tid >> 6);
        int lane = tid & 63;
        const float* xr = x + (size_t)row * DIN + lane * 16;
        float xv[16];
        *(float4*)&xv[0]  = *(const float4*)(xr);
        *(float4*)&xv[4]  = *(const float4*)(xr + 4);
        *(float4*)&xv[8]  = *(const float4*)(xr + 8);
        *(float4*)&xv[12] = *(const float4*)(xr + 12);
        asm volatile("" ::: "memory");   // keep all 4 loads in flight
        const float* w1 = wa1 + lane * 16;
        const float* w2 = wa2 + lane * 16;
        float s1 = 0.f, s2 = 0.f;
#pragma unroll
        for (int j = 0; j < 16; ++j) {
            s1 += xv[j] * w1[j];
            s2 += xv[j] * w2[j];
        }
        union { unsigned short u[8]; uint4 q; } pk0, pk1;
#pragma unroll
        for (int j = 0; j < 8; ++j) { pk0.u[j] = f2bf(xv[j]); pk1.u[j] = f2bf(xv[8 + j]); }
        int sw = (row >> 1) & 3;
        int g0 = lane * 2, g1 = lane * 2 + 1;
        int p0 = (g0 & ~3) | ((g0 & 3) ^ sw);
        int p1 = (g1 & ~3) | ((g1 & 3) ^ sw);
        unsigned short* xrow = xb + (size_t)row * DIN;
        *(uint4*)(xrow + p0 * 8) = pk0.q;
        *(uint4*)(xrow + p1 * 8) = pk1.q;
        for (int off = 32; off; off >>= 1) {
            s1 += __shfl_down(s1, off);
            s2 += __shfl_down(s2, off);
        }
        if (lane == 0) { f1[row] = s1 + b1[0]; f2[row] = s2 + b2[0]; }
    }
}

// ---------------- K3: Z via bitmask walk (wave per row, 4 rows/block) -> rZ
// u64 at lane l = 4 consecutive u16 thread-masks. Bit b ->
//   col j = 16*l + 4*(b>>4) + 1024*((b>>2)&3) + (b&3)
__global__ __launch_bounds__(256) void k_z(const unsigned long long* __restrict__ bits,
                                           const float* __restrict__ f1,
                                           const float* __restrict__ f2,
                                           float* __restrict__ rZ_out) {
    int row  = blockIdx.x * 4 + (threadIdx.x >> 6);
    int lane = threadIdx.x & 63;
    unsigned long long w = bits[(size_t)row * 64 + lane];
    float f1r = f1[row];
    float z = 0.f;
    while (w) {
        int b = __builtin_ctzll(w);
        w &= w - 1;
        int j = 16 * lane + 4 * (b >> 4) + 1024 * ((b >> 2) & 3) + (b & 3);
        float l = f1r + f2[j];
        z += __expf((l >= 0.f) ? l : ALPHA * l);
    }
    for (int off = 32; off; off >>= 1) z += __shfl_down(z, off);
    if (lane == 0) rZ_out[row] = 1.0f / z;
}

// ---------------- K4: colsum via bitmask walk (wave per row) -> s
__global__ __launch_bounds__(256) void k_s(const unsigned long long* __restrict__ bits,
                                           const float* __restrict__ f1,
                                           const float* __restrict__ f2,
                                           const float* __restrict__ rZ,
                                           float* __restrict__ s_out) {
    int row  = blockIdx.x * 4 + (threadIdx.x >> 6);
    int lane = threadIdx.x & 63;
    unsigned long long w = bits[(size_t)row * 64 + lane];
    float f2r = f2[row];
    float sum = 0.f;
    while (w) {
        int b = __builtin_ctzll(w);
        w &= w - 1;
        int j = 16 * lane + 4 * (b >> 4) + 1024 * ((b >> 2) & 3) + (b & 3);
        float l = f1[j] + f2r;
        float e = (l >= 0.f) ? l : ALPHA * l;
        sum += __expf(e) * rZ[j];
    }
    for (int off = 32; off; off >>= 1) sum += __shfl_down(sum, off);
    if (lane == 0) {
        float l   = f1[row] + f2r;
        float e   = (l >= 0.f) ? l : ALPHA * l;
        float cjj = __expf(e) * rZ[row];
        s_out[row] = (cjj + 1.0f) / (1.5f + 0.5f * sum);
    }
}

// ---------------- K5: out = relu(diag(s) @ (xb @ Wt^T)), bf16 MFMA
// 128x64 tile, BK=32, 4 waves each 64x32, double-buffered global_load_lds.
__global__ __launch_bounds__(256) void k_gemm(const unsigned short* __restrict__ xb,
                                              const unsigned short* __restrict__ wt,
                                              const float* __restrict__ s,
                                              float* __restrict__ out) {
    __shared__ __align__(16) unsigned short As[2][128][32];
    __shared__ __align__(16) unsigned short Bs[2][64][32];
    // XCD-chunked block remap: each XCD gets 4 consecutive M-strips x all N.
    int lid = blockIdx.y * gridDim.x + blockIdx.x;   // 0..255
    int xcd = lid & 7, idx = lid >> 3;
    int by = xcd * 4 + (idx & 3);                    // 0..31
    int bx = idx >> 2;                               // 0..7
    int bm = by * 128, bn = bx * 64;

    int tid = threadIdx.x, wid = tid >> 6, lane = tid & 63;
    int wr = wid >> 1, wc = wid & 1;

    // staging: per-lane global source (linear; swizzle is baked into xb/wt)
    int srow = lane >> 2, sg = lane & 3;
    const unsigned short* ga0 = xb + (size_t)(bm + wid * 32 + srow) * DIN + sg * 8;
    const unsigned short* gb0 = wt + (size_t)(bn + wid * 16 + srow) * DIN + sg * 8;

    int r15 = lane & 15, gl = lane >> 4;
    int gofs = (gl ^ ((r15 >> 1) & 3)) * 8;          // XOR-swizzled read offset

    f32x4 acc[4][2] = {};

#define STAGE(BUF, K0) do {                                              \
        async16(ga0 + (K0),            &As[BUF][wid * 32][0]);           \
        async16(ga0 + (K0) + 16 * DIN, &As[BUF][wid * 32 + 16][0]);      \
        async16(gb0 + (K0),            &Bs[BUF][wid * 16][0]);           \
    } while (0)

#define COMPUTE(BUF) do {                                                \
        const unsigned short* pa = &As[BUF][wr * 64 + r15][gofs];        \
        const unsigned short* pb = &Bs[BUF][wc * 32 + r15][gofs];        \
        short8 af0 = *(const short8*)(pa);                               \
        short8 af1 = *(const short8*)(pa + 16 * 32);                     \
        short8 af2 = *(const short8*)(pa + 32 * 32);                     \
        short8 af3 = *(const short8*)(pa + 48 * 32);                     \
        short8 bf0 = *(const short8*)(pb);                               \
        short8 bf1 = *(const short8*)(pb + 16 * 32);                     \
        acc[0][0] = __builtin_amdgcn_mfma_f32_16x16x32_bf16(af0, bf0, acc[0][0], 0, 0, 0); \
        acc[0][1] = __builtin_amdgcn_mfma_f32_16x16x32_bf16(af0, bf1, acc[0][1], 0, 0, 0); \
        acc[1][0] = __builtin_amdgcn_mfma_f32_16x16x32_bf16(af1, bf0, acc[1][0], 0, 0, 0); \
        acc[1][1] = __builtin_amdgcn_mfma_f32_16x16x32_bf16(af1, bf1, acc[1][1], 0, 0, 0); \
        acc[2][0] = __builtin_amdgcn_mfma_f32_16x16x32_bf16(af2, bf0, acc[2][0], 0, 0, 0); \
        acc[2][1] = __builtin_amdgcn_mfma_f32_16x16x32_bf16(af2, bf1, acc[2][1], 0, 0, 0); \
        acc[3][0] = __builtin_amdgcn_mfma_f32_16x16x32_bf16(af3, bf0, acc[3][0], 0, 0, 0); \
        acc[3][1] = __builtin_amdgcn_mfma_f32_16x16x32_bf16(af3, bf1, acc[3][1], 0, 0, 0); \
    } while (0)

    STAGE(0, 0);
    asm volatile("s_waitcnt vmcnt(0)" ::: "memory");
    __syncthreads();
    int cur = 0;
    for (int t = 0; t < (DIN / 32) - 1; ++t) {
        STAGE(cur ^ 1, (t + 1) * 32);
        COMPUTE(cur);
        asm volatile("s_waitcnt vmcnt(0)" ::: "memory");
        __syncthreads();
        cur ^= 1;
    }
    COMPUTE(cur);

#pragma unroll
    for (int mi = 0; mi < 4; ++mi) {
        int crow0 = bm + wr * 64 + mi * 16 + gl * 4;
#pragma unroll
        for (int ni = 0; ni < 2; ++ni) {
            int ccol = bn + wc * 32 + ni * 16 + r15;
#pragma unroll
            for (int r = 0; r < 4; ++r) {
                int row = crow0 + r;
                float v = acc[mi][ni][r] * s[row];
                out[(size_t)row * DOUT + ccol] = fmaxf(v, 0.f);
            }
        }
    }
#undef STAGE
#undef COMPUTE
}

extern "C" void kernel_launch(void* const* d_in, const int* in_sizes, int n_in,
                              void* d_out, int out_size, void* d_ws, size_t ws_size,
                              hipStream_t stream) {
    const float* x   = (const float*)d_in[0];
    const float* adj = (const float*)d_in[1];
    const float* Wf  = (const float*)d_in[2];
    const float* a1  = (const float*)d_in[3];
    const float* b1  = (const float*)d_in[4];
    const float* a2  = (const float*)d_in[5];
    const float* b2  = (const float*)d_in[6];
    const float* W   = (const float*)d_in[7];
    float* out = (float*)d_out;

    char* w = (char*)d_ws;
    float* wa1 = (float*)(w + 0);
    float* wa2 = (float*)(w + 4096);
    float* f1  = (float*)(w + 16384);
    float* f2  = (float*)(w + 32768);
    float* rZ  = (float*)(w + 49152);
    float* s   = (float*)(w + 65536);
    unsigned short* bits16 = (unsigned short*)(w + 98304);           // 2 MB
    unsigned short* xb = (unsigned short*)(w + 2195456);             // 8 MB
    unsigned short* wt = (unsigned short*)(w + 10584064);            // 1 MB

    k_prep<<<512, 256, 0, stream>>>(W, Wf, a1, a2, wt, wa1, wa2);
    k_maskfx<<<3072, 256, 0, stream>>>(adj, x, wa1, wa2, b1, b2, f1, f2, xb, bits16);
    k_z<<<1024, 256, 0, stream>>>((const unsigned long long*)bits16, f1, f2, rZ);
    k_s<<<1024, 256, 0, stream>>>((const unsigned long long*)bits16, f1, f2, rZ, s);
    dim3 gg(8, 32);
    k_gemm<<<gg, 256, 0, stream>>>(xb, wt, s, out);
}

// Round 11
// 50.370 us; speedup vs baseline: 1.1977x; 1.0137x over previous
//
#include <hip/hip_runtime.h>
#include <stdint.h>
#include <math.h>

#define NN 4096
#define DIN 1024
#define DOUT 512
#define ALPHA 0.2f

typedef __attribute__((ext_vector_type(8))) short short8;
typedef __attribute__((ext_vector_type(4))) float f32x4;

__device__ __forceinline__ unsigned short f2bf(float f) {
    uint32_t u = __float_as_uint(f);
    u += 0x7fffu + ((u >> 16) & 1u);
    return (unsigned short)(u >> 16);
}

__device__ __forceinline__ void async16(const void* g, void* l) {
    __builtin_amdgcn_global_load_lds(
        (const __attribute__((address_space(1))) uint32_t*)g,
        (__attribute__((address_space(3))) uint32_t*)l, 16, 0, 0);
}

// ---------------- K1: fused prep.
// blocks 0..255:   wt = bf16(W^T) with pre-swizzled granules
// blocks 256..511: wa1 = Wf@a1, wa2 = Wf@a2 (wave per row)
__global__ __launch_bounds__(256) void k_prep(const float* __restrict__ W,
                                              const float* __restrict__ Wf,
                                              const float* __restrict__ a1,
                                              const float* __restrict__ a2,
                                              unsigned short* __restrict__ wt,
                                              float* __restrict__ wa1,
                                              float* __restrict__ wa2) {
    int tid = threadIdx.x;
    if (blockIdx.x < 256) {
        int bx = blockIdx.x & 7, gy = blockIdx.x >> 3;
        int n = bx * 64 + (tid & 63);
        int g = gy * 4 + (tid >> 6);          // k-granule 0..127
        float v[8];
#pragma unroll
        for (int j = 0; j < 8; ++j) v[j] = W[(size_t)(g * 8 + j) * DOUT + n];
        union { unsigned short u[8]; uint4 q; } pk;
#pragma unroll
        for (int j = 0; j < 8; ++j) pk.u[j] = f2bf(v[j]);
        int sw = (n >> 1) & 3;
        int p  = (g & ~3) | ((g & 3) ^ sw);
        *(uint4*)(wt + (size_t)n * DIN + p * 8) = pk.q;
    } else {
        int row  = (blockIdx.x - 256) * 4 + (tid >> 6);
        int lane = tid & 63;
        const float* wr = Wf + (size_t)row * DOUT;
        float s1 = 0.f, s2 = 0.f;
        for (int k = lane; k < DOUT; k += 64) {
            float w = wr[k];
            s1 += w * a1[k];
            s2 += w * a2[k];
        }
        for (int off = 32; off; off >>= 1) {
            s1 += __shfl_down(s1, off);
            s2 += __shfl_down(s2, off);
        }
        if (lane == 0) { wa1[row] = s1; wa2[row] = s2; }
    }
}

// ---------------- K2: fused mask-builder + fx.
// blocks 0..2047: PURE adj stream -> u16 masks (2 rows/block, 8 loads kept
// in flight via sched_barrier(0) -- a "memory" clobber does NOT stop VALU
// consumers from hoisting between loads, rule #18)
// blocks 2048..3071: f1,f2 GEMV + x -> bf16 (wave per row)
__global__ __launch_bounds__(256) void k_maskfx(const float* __restrict__ adj,
    const float* __restrict__ x,
    const float* __restrict__ wa1, const float* __restrict__ wa2,
    const float* __restrict__ b1, const float* __restrict__ b2,
    float* __restrict__ f1, float* __restrict__ f2,
    unsigned short* __restrict__ xb,
    unsigned short* __restrict__ bits16) {
    int tid = threadIdx.x;
    if (blockIdx.x < 2048) {
        int row0 = blockIdx.x * 2;
        const float4* a0 = (const float4*)(adj + (size_t)row0 * NN);
        const float4* a1v = (const float4*)(adj + (size_t)(row0 + 1) * NN);
        float4 v0 = a0[tid];        float4 v1 = a0[tid + 256];
        float4 v2 = a0[tid + 512];  float4 v3 = a0[tid + 768];
        float4 v4 = a1v[tid];       float4 v5 = a1v[tid + 256];
        float4 v6 = a1v[tid + 512]; float4 v7 = a1v[tid + 768];
        __builtin_amdgcn_sched_barrier(0);   // hard fence: all 8 loads issue first
        unsigned int m0 = 0, m1 = 0;
#define MB(M, V, J)                                            \
        M |= (((V).x != 0.f) ? 1u : 0u) << (4 * (J));          \
        M |= (((V).y != 0.f) ? 1u : 0u) << (4 * (J) + 1);      \
        M |= (((V).z != 0.f) ? 1u : 0u) << (4 * (J) + 2);      \
        M |= (((V).w != 0.f) ? 1u : 0u) << (4 * (J) + 3);
        MB(m0, v0, 0) MB(m0, v1, 1) MB(m0, v2, 2) MB(m0, v3, 3)
        MB(m1, v4, 0) MB(m1, v5, 1) MB(m1, v6, 2) MB(m1, v7, 3)
#undef MB
        bits16[(size_t)row0 * 256 + tid]       = (unsigned short)m0;
        bits16[(size_t)row0 * 256 + 256 + tid] = (unsigned short)m1;
    } else {
        int row  = (blockIdx.x - 2048) * 4 + (tid >> 6);
        int lane = tid & 63;
        const float* xr = x + (size_t)row * DIN + lane * 16;
        float xv[16];
        *(float4*)&xv[0]  = *(const float4*)(xr);
        *(float4*)&xv[4]  = *(const float4*)(xr + 4);
        *(float4*)&xv[8]  = *(const float4*)(xr + 8);
        *(float4*)&xv[12] = *(const float4*)(xr + 12);
        __builtin_amdgcn_sched_barrier(0);   // all 4 loads in flight
        const float* w1 = wa1 + lane * 16;
        const float* w2 = wa2 + lane * 16;
        float s1 = 0.f, s2 = 0.f;
#pragma unroll
        for (int j = 0; j < 16; ++j) {
            s1 += xv[j] * w1[j];
            s2 += xv[j] * w2[j];
        }
        union { unsigned short u[8]; uint4 q; } pk0, pk1;
#pragma unroll
        for (int j = 0; j < 8; ++j) { pk0.u[j] = f2bf(xv[j]); pk1.u[j] = f2bf(xv[8 + j]); }
        int sw = (row >> 1) & 3;
        int g0 = lane * 2, g1 = lane * 2 + 1;
        int p0 = (g0 & ~3) | ((g0 & 3) ^ sw);
        int p1 = (g1 & ~3) | ((g1 & 3) ^ sw);
        unsigned short* xrow = xb + (size_t)row * DIN;
        *(uint4*)(xrow + p0 * 8) = pk0.q;
        *(uint4*)(xrow + p1 * 8) = pk1.q;
        for (int off = 32; off; off >>= 1) {
            s1 += __shfl_down(s1, off);
            s2 += __shfl_down(s2, off);
        }
        if (lane == 0) { f1[row] = s1 + b1[0]; f2[row] = s2 + b2[0]; }
    }
}

// ---------------- K3: Z via bitmask walk (wave per row, 4 rows/block) -> rZ
// u64 at lane l = 4 consecutive u16 thread-masks. Bit b ->
//   col j = 16*l + 4*(b>>4) + 1024*((b>>2)&3) + (b&3)
__global__ __launch_bounds__(256) void k_z(const unsigned long long* __restrict__ bits,
                                           const float* __restrict__ f1,
                                           const float* __restrict__ f2,
                                           float* __restrict__ rZ_out) {
    int row  = blockIdx.x * 4 + (threadIdx.x >> 6);
    int lane = threadIdx.x & 63;
    unsigned long long w = bits[(size_t)row * 64 + lane];
    float f1r = f1[row];
    float z = 0.f;
    while (w) {
        int b = __builtin_ctzll(w);
        w &= w - 1;
        int j = 16 * lane + 4 * (b >> 4) + 1024 * ((b >> 2) & 3) + (b & 3);
        float l = f1r + f2[j];
        z += __expf((l >= 0.f) ? l : ALPHA * l);
    }
    for (int off = 32; off; off >>= 1) z += __shfl_down(z, off);
    if (lane == 0) rZ_out[row] = 1.0f / z;
}

// ---------------- K4: colsum via bitmask walk (wave per row) -> s
__global__ __launch_bounds__(256) void k_s(const unsigned long long* __restrict__ bits,
                                           const float* __restrict__ f1,
                                           const float* __restrict__ f2,
                                           const float* __restrict__ rZ,
                                           float* __restrict__ s_out) {
    int row  = blockIdx.x * 4 + (threadIdx.x >> 6);
    int lane = threadIdx.x & 63;
    unsigned long long w = bits[(size_t)row * 64 + lane];
    float f2r = f2[row];
    float sum = 0.f;
    while (w) {
        int b = __builtin_ctzll(w);
        w &= w - 1;
        int j = 16 * lane + 4 * (b >> 4) + 1024 * ((b >> 2) & 3) + (b & 3);
        float l = f1[j] + f2r;
        float e = (l >= 0.f) ? l : ALPHA * l;
        sum += __expf(e) * rZ[j];
    }
    for (int off = 32; off; off >>= 1) sum += __shfl_down(sum, off);
    if (lane == 0) {
        float l   = f1[row] + f2r;
        float e   = (l >= 0.f) ? l : ALPHA * l;
        float cjj = __expf(e) * rZ[row];
        s_out[row] = (cjj + 1.0f) / (1.5f + 0.5f * sum);
    }
}

// ---------------- K5: out = relu(diag(s) @ (xb @ Wt^T)), bf16 MFMA
// 128x64 tile, BK=32, 4 waves each 64x32, double-buffered global_load_lds.
__global__ __launch_bounds__(256) void k_gemm(const unsigned short* __restrict__ xb,
                                              const unsigned short* __restrict__ wt,
                                              const float* __restrict__ s,
                                              float* __restrict__ out) {
    __shared__ __align__(16) unsigned short As[2][128][32];
    __shared__ __align__(16) unsigned short Bs[2][64][32];
    // XCD-chunked block remap: each XCD gets 4 consecutive M-strips x all N.
    int lid = blockIdx.y * gridDim.x + blockIdx.x;   // 0..255
    int xcd = lid & 7, idx = lid >> 3;
    int by = xcd * 4 + (idx & 3);                    // 0..31
    int bx = idx >> 2;                               // 0..7
    int bm = by * 128, bn = bx * 64;

    int tid = threadIdx.x, wid = tid >> 6, lane = tid & 63;
    int wr = wid >> 1, wc = wid & 1;

    // staging: per-lane global source (linear; swizzle is baked into xb/wt)
    int srow = lane >> 2, sg = lane & 3;
    const unsigned short* ga0 = xb + (size_t)(bm + wid * 32 + srow) * DIN + sg * 8;
    const unsigned short* gb0 = wt + (size_t)(bn + wid * 16 + srow) * DIN + sg * 8;

    int r15 = lane & 15, gl = lane >> 4;
    int gofs = (gl ^ ((r15 >> 1) & 3)) * 8;          // XOR-swizzled read offset

    f32x4 acc[4][2] = {};

#define STAGE(BUF, K0) do {                                              \
        async16(ga0 + (K0),            &As[BUF][wid * 32][0]);           \
        async16(ga0 + (K0) + 16 * DIN, &As[BUF][wid * 32 + 16][0]);      \
        async16(gb0 + (K0),            &Bs[BUF][wid * 16][0]);           \
    } while (0)

#define COMPUTE(BUF) do {                                                \
        const unsigned short* pa = &As[BUF][wr * 64 + r15][gofs];        \
        const unsigned short* pb = &Bs[BUF][wc * 32 + r15][gofs];        \
        short8 af0 = *(const short8*)(pa);                               \
        short8 af1 = *(const short8*)(pa + 16 * 32);                     \
        short8 af2 = *(const short8*)(pa + 32 * 32);                     \
        short8 af3 = *(const short8*)(pa + 48 * 32);                     \
        short8 bf0 = *(const short8*)(pb);                               \
        short8 bf1 = *(const short8*)(pb + 16 * 32);                     \
        acc[0][0] = __builtin_amdgcn_mfma_f32_16x16x32_bf16(af0, bf0, acc[0][0], 0, 0, 0); \
        acc[0][1] = __builtin_amdgcn_mfma_f32_16x16x32_bf16(af0, bf1, acc[0][1], 0, 0, 0); \
        acc[1][0] = __builtin_amdgcn_mfma_f32_16x16x32_bf16(af1, bf0, acc[1][0], 0, 0, 0); \
        acc[1][1] = __builtin_amdgcn_mfma_f32_16x16x32_bf16(af1, bf1, acc[1][1], 0, 0, 0); \
        acc[2][0] = __builtin_amdgcn_mfma_f32_16x16x32_bf16(af2, bf0, acc[2][0], 0, 0, 0); \
        acc[2][1] = __builtin_amdgcn_mfma_f32_16x16x32_bf16(af2, bf1, acc[2][1], 0, 0, 0); \
        acc[3][0] = __builtin_amdgcn_mfma_f32_16x16x32_bf16(af3, bf0, acc[3][0], 0, 0, 0); \
        acc[3][1] = __builtin_amdgcn_mfma_f32_16x16x32_bf16(af3, bf1, acc[3][1], 0, 0, 0); \
    } while (0)

    STAGE(0, 0);
    asm volatile("s_waitcnt vmcnt(0)" ::: "memory");
    __syncthreads();
    int cur = 0;
    for (int t = 0; t < (DIN / 32) - 1; ++t) {
        STAGE(cur ^ 1, (t + 1) * 32);
        COMPUTE(cur);
        asm volatile("s_waitcnt vmcnt(0)" ::: "memory");
        __syncthreads();
        cur ^= 1;
    }
    COMPUTE(cur);

#pragma unroll
    for (int mi = 0; mi < 4; ++mi) {
        int crow0 = bm + wr * 64 + mi * 16 + gl * 4;
#pragma unroll
        for (int ni = 0; ni < 2; ++ni) {
            int ccol = bn + wc * 32 + ni * 16 + r15;
#pragma unroll
            for (int r = 0; r < 4; ++r) {
                int row = crow0 + r;
                float v = acc[mi][ni][r] * s[row];
                out[(size_t)row * DOUT + ccol] = fmaxf(v, 0.f);
            }
        }
    }
#undef STAGE
#undef COMPUTE
}

extern "C" void kernel_launch(void* const* d_in, const int* in_sizes, int n_in,
                              void* d_out, int out_size, void* d_ws, size_t ws_size,
                              hipStream_t stream) {
    const float* x   = (const float*)d_in[0];
    const float* adj = (const float*)d_in[1];
    const float* Wf  = (const float*)d_in[2];
    const float* a1  = (const float*)d_in[3];
    const float* b1  = (const float*)d_in[4];
    const float* a2  = (const float*)d_in[5];
    const float* b2  = (const float*)d_in[6];
    const float* W   = (const float*)d_in[7];
    float* out = (float*)d_out;

    char* w = (char*)d_ws;
    float* wa1 = (float*)(w + 0);
    float* wa2 = (float*)(w + 4096);
    float* f1  = (float*)(w + 16384);
    float* f2  = (float*)(w + 32768);
    float* rZ  = (float*)(w + 49152);
    float* s   = (float*)(w + 65536);
    unsigned short* bits16 = (unsigned short*)(w + 98304);           // 2 MB
    unsigned short* xb = (unsigned short*)(w + 2195456);             // 8 MB
    unsigned short* wt = (unsigned short*)(w + 10584064);            // 1 MB

    k_prep<<<512, 256, 0, stream>>>(W, Wf, a1, a2, wt, wa1, wa2);
    k_maskfx<<<3072, 256, 0, stream>>>(adj, x, wa1, wa2, b1, b2, f1, f2, xb, bits16);
    k_z<<<1024, 256, 0, stream>>>((const unsigned long long*)bits16, f1, f2, rZ);
    k_s<<<1024, 256, 0, stream>>>((const unsigned long long*)bits16, f1, f2, rZ, s);
    dim3 gg(8, 32);
    k_gemm<<<gg, 256, 0, stream>>>(xb, wt, s, out);
}